// Round 13
// baseline (229.310 us; speedup 1.0000x reference)
//
#include <hip/hip_runtime.h>
#include <math.h>

#define HD   64
#define EIN  8
#define SAS  168          // !HB: full bf16 W1 row stride in u16
#define W2S  72           // !HB: sW2/X1 row stride in u16 (144 B)
#define X1BS 72           // HB: X1 fp8 row stride in BYTES (16 banks, conflict-free)
#define NORM_INV 0.01f
#define NTH  256
#define NBLK 1536         // 6 blocks/CU: r14/r16 A/B proved this is the optimum
#define NWAVES (NBLK * (NTH / 64))

typedef short bf16x8 __attribute__((ext_vector_type(8)));
typedef float f32x4  __attribute__((ext_vector_type(4)));
typedef float f4v    __attribute__((ext_vector_type(4)));

__device__ __forceinline__ unsigned short f2bf(float f) {
    union { float f; unsigned u; } v; v.f = f;
    unsigned r = v.u + 0x7FFFu + ((v.u >> 16) & 1u);
    return (unsigned short)(r >> 16);
}
__device__ __forceinline__ unsigned pk2(float a, float b) {
    return (unsigned)f2bf(a) | ((unsigned)f2bf(b) << 16);
}
// single-instruction packed f32->2xbf16 (RNE)
__device__ __forceinline__ unsigned cvt_pk_bf16(float lo, float hi) {
    unsigned r;
    asm("v_cvt_pk_bf16_f32 %0, %1, %2" : "=v"(r) : "v"(lo), "v"(hi));
    return r;
}
__device__ __forceinline__ float silu_f(float x) {
    return x * __builtin_amdgcn_rcpf(1.0f + __expf(-x));
}
// pair-silu: ONE rcp for two values (exact algebra, one extra rounding)
__device__ __forceinline__ void silu2(float x, float y, float& sx, float& sy) {
    float a = 1.0f + __expf(-x);
    float b = 1.0f + __expf(-y);
    float r = __builtin_amdgcn_rcpf(a * b);
    sx = x * (b * r);
    sy = y * (a * r);
}
__device__ __forceinline__ bf16x8 pack_f8(f4v a, f4v b) {
    union { bf16x8 v; uint4 u; } pk;
    pk.u.x = pk2(a.x, a.y); pk.u.y = pk2(a.z, a.w);
    pk.u.z = pk2(b.x, b.y); pk.u.w = pk2(b.z, b.w);
    return pk.v;
}

// prep: h -> fp8 e4m3 table in ws + coord -> out copy + zero the partition accumulators
__global__ void prep_h_kernel(const float* __restrict__ h, unsigned char* __restrict__ hf8,
                              int nq, const float* __restrict__ coord,
                              float* __restrict__ out, int n3,
                              float* __restrict__ zbase, int zcount) {
    int i = blockIdx.x * blockDim.x + threadIdx.x;
    if (i < nq) {
        f4v v = reinterpret_cast<const f4v*>(h)[i];
        int p = __builtin_amdgcn_cvt_pk_fp8_f32(v.x, v.y, 0, false);
        p     = __builtin_amdgcn_cvt_pk_fp8_f32(v.z, v.w, p, true);
        reinterpret_cast<int*>(hf8)[i] = p;
    }
    if (i < n3) out[i] = coord[i];
    for (int j = i; j < zcount; j += gridDim.x * blockDim.x) zbase[j] = 0.f;
}

__global__ void prep_out_kernel(const float* __restrict__ coord,
                                float* __restrict__ out, int n3) {
    int i = blockIdx.x * blockDim.x + threadIdx.x;
    if (i < n3) out[i] = coord[i];
}

// final: out = coord + sum over partition accumulator copies
__global__ void reduce_out_kernel(const float* __restrict__ coord,
                                  const float* __restrict__ copies,
                                  float* __restrict__ out, int n3, int nc) {
    int i = blockIdx.x * blockDim.x + threadIdx.x;
    if (i < n3) {
        float s = coord[i];
        for (int c = 0; c < nc; ++c) s += copies[(size_t)c * n3 + i];
        out[i] = s;
    }
}

// r18 ledger:
//  r17 bench: container failed twice (no counters). Prime suspect: raw
//    s_getreg(HW_REG_XCC_ID) inline asm. The theory never needed the TRUE
//    XCD id -- partitioning atomics across 8 disjoint accumulators gives the
//    8x per-line contention cut regardless, and blockIdx.x & 7 matches the
//    round-robin workgroup->XCD dispatch anyway (same property as the T1
//    swizzle). This round: identical r17 plan, blockIdx-based partition,
//    zero special-register asm.
//  Standing theory (r16 counters): WRITE_SIZE 62.4 MB for a 600 KB output =
//    100x write amplification = 4.8M device-scope atomics, 8 XCDs RMW-ing
//    the same hot lines memory-side; in-order vmcnt puts that latency on
//    every iteration's critical path. Fits every flat result (occupancy/
//    prefetch/VALU all neutral).
//  Keystones: main-kernel WRITE < 10MB; dur 80-95us if atomics were the
//    binder (flat + WRITE collapsed -> structural floor, declare).
template <bool HB>
__global__ __launch_bounds__(NTH, 5) void egnn_mfma_kernel(
    const float* __restrict__ h,             // fp32 h (when !HB)
    const unsigned char* __restrict__ hf8,   // fp8 h table in ws (when HB)
    const float* __restrict__ coord,
    const int*   __restrict__ eidx,   // [2][E]
    const float* __restrict__ eattr,  // [E][8]
    const float* __restrict__ W1f,    // [136][64] fp32 (k-major)
    const float* __restrict__ W2f,    // [64][64] fp32 (k-major)
    const float* __restrict__ b1,
    const float* __restrict__ b2,
    const float* __restrict__ W3,
    float* __restrict__ obase,        // out (ncmask=0) or partition copies base
    int ncmask,                       // ncopies-1 (0 = direct)
    int n3r,                          // N*3 (copy stride)
    int E_)
{
    constexpr int LDS_BYTES = HB ? 18688 : 40704;
    __shared__ __align__(16) char lds[LDS_BYTES];

    unsigned long*  sW1f8 = (unsigned long*)lds;                         // HB
    unsigned short* sW1b  = (unsigned short*)(lds + 8192);               // HB
    unsigned long*  sW2f8 = (unsigned long*)(lds + 9216);                // HB
    unsigned char*  sX1b  = (unsigned char*)(lds + 13312);               // HB
    unsigned short* sW1   = (unsigned short*)lds;                        // !HB
    unsigned short* sW2   = (unsigned short*)(lds + 21504);              // !HB
    unsigned short* sX1   = (unsigned short*)(lds + 30720);              // !HB
    float*          sB1   = (float*)(lds + (HB ? 17920 : 39936));
    float*          sB2   = sB1 + 64;
    float*          sW3   = sB1 + 128;

    const int t = threadIdx.x;

    // ---- weights -> LDS (once per block) ----
    if (HB) {
        for (int f = t; f < 16 * 64; f += NTH) {
            int frag = f >> 6, ln = f & 63;
            int nt = frag >> 2, s = frag & 3;
            int mm = ln & 15, qq = ln >> 4;
            int n2 = nt * 16 + mm, kb = s * 32 + qq * 8;
            unsigned long v = 0;
#pragma unroll
            for (int j = 0; j < 8; j += 2) {
                float a = W1f[(kb + j) * 64 + n2] * 8.0f;
                float b = W1f[(kb + j + 1) * 64 + n2] * 8.0f;
                int p = __builtin_amdgcn_cvt_pk_fp8_f32(a, b, 0, false);
                v |= ((unsigned long)(unsigned)(p & 0xFFFF)) << (j * 8);
            }
            sW1f8[f] = v;
        }
        for (int i = t; i < 64 * 8; i += NTH) {
            int n2 = i >> 3, kk = i & 7;
            sW1b[i] = f2bf(W1f[(128 + kk) * 64 + n2]);
        }
        for (int f = t; f < 8 * 64; f += NTH) {
            int frag = f >> 6, ln = f & 63;
            int nt = frag >> 1, s = frag & 1;
            int mm = ln & 15, qq = ln >> 4;
            int n2 = nt * 16 + mm, kb = s * 32 + qq * 8;
            unsigned long v = 0;
#pragma unroll
            for (int j = 0; j < 8; j += 2) {
                float a = W2f[(kb + j) * 64 + n2] * 8.0f;
                float b = W2f[(kb + j + 1) * 64 + n2] * 8.0f;
                int p = __builtin_amdgcn_cvt_pk_fp8_f32(a, b, 0, false);
                v |= ((unsigned long)(unsigned)(p & 0xFFFF)) << (j * 8);
            }
            sW2f8[f] = v;
        }
    } else {
        for (int i = t; i < 136 * 64; i += NTH) {
            int k = i >> 6, n = i & 63;
            sW1[n * SAS + k] = f2bf(W1f[i]);
        }
        for (int i = t; i < 24 * 64; i += NTH) {
            int n = i / 24, k = 136 + (i - n * 24);
            sW1[n * SAS + k] = 0;
        }
        for (int i = t; i < 64 * 64; i += NTH) {
            int k = i >> 6, n = i & 63;
            sW2[n * W2S + k] = f2bf(W2f[i]);
        }
    }
    if (t < 64) sB1[t] = b1[t];
    else if (t < 128) sB2[t - 64] = b2[t - 64];
    else if (t < 192) sW3[t - 128] = W3[t - 128];
    __syncthreads();                               // the ONLY barrier

    const int w = t >> 6, lane = t & 63;
    const int m = lane & 15, q = lane >> 4;

    // partition sink: blockIdx & 7 ~ physical XCD under round-robin dispatch
    float* osink = obase + (size_t)(blockIdx.x & ncmask) * n3r;

    unsigned char*  x1RowB = sX1b + (16 * w + m) * X1BS;          // HB
    unsigned short* x1Row  = sX1 + (16 * w + m) * W2S;            // !HB

    const int ngroups = (E_ + 15) >> 4;
    for (int g = blockIdx.x * (NTH / 64) + w; g < ngroups; g += NWAVES) {
        int e = g * 16 + m;
        int ec = (e < E_) ? e : (E_ - 1);
        int row = __builtin_nontemporal_load(eidx + ec);
        int col = __builtin_nontemporal_load(eidx + (size_t)E_ + ec);

        // coord loads issued early (L2-resident table)
        float cr = 0.f, cc = 0.f;
        if (q < 3) { cr = coord[row * 3 + q]; cc = coord[col * 3 + q]; }

        // ---------- eattr fragment (bf16, k=128..135 on q==0) ----------
        bf16x8 bf4;
        {
            union { bf16x8 v; uint4 u; } pk;
            pk.u.x = 0; pk.u.y = 0; pk.u.z = 0; pk.u.w = 0;
            if (q == 0) {
                const f4v* ea = (const f4v*)(eattr + (size_t)ec * EIN);
                f4v a0 = __builtin_nontemporal_load(ea);
                f4v a1 = __builtin_nontemporal_load(ea + 1);
                pk.u.x = cvt_pk_bf16(a0.x, a0.y);
                pk.u.y = cvt_pk_bf16(a0.z, a0.w);
                pk.u.z = cvt_pk_bf16(a1.x, a1.y);
                pk.u.w = cvt_pk_bf16(a1.z, a1.w);
            }
            bf4 = pk.v;
        }

        f32x4 acc1[4] = {};

        if (HB) {
            // ---------- layer-1 h-part: fp8 gathers (8 B each, L2-resident) ----------
            const unsigned long* hr8 = (const unsigned long*)(hf8 + (size_t)row * HD);
            const unsigned long* hc8 = (const unsigned long*)(hf8 + (size_t)col * HD);
            long b0 = (long)hr8[q];         // k =      q*8
            long b1v = (long)hr8[4 + q];    // k = 32 + q*8
            long b2v = (long)hc8[q];        // k = 64 + ...
            long b3v = (long)hc8[4 + q];    // k = 96 + ...
            __builtin_amdgcn_s_setprio(1);
#define L1F8(S, B)                                                            \
            _Pragma("unroll")                                                 \
            for (int nt = 0; nt < 4; ++nt) {                                  \
                long a8 = (long)sW1f8[((nt << 2) | (S)) * 64 + lane];         \
                acc1[nt] = __builtin_amdgcn_mfma_f32_16x16x32_fp8_fp8(a8, B, acc1[nt], 0, 0, 0); \
            }
            L1F8(0, b0)
            L1F8(1, b1v)
            L1F8(2, b2v)
            L1F8(3, b3v)
#undef L1F8
            // eattr tail (bf16 MFMA): broadcast-read, q>=1 slices killed by zeros.
#pragma unroll
            for (int nt = 0; nt < 4; ++nt) {
                bf16x8 afb = *(const bf16x8*)(sW1b + (16 * nt + m) * 8);
                acc1[nt] = __builtin_amdgcn_mfma_f32_16x16x32_bf16(afb, bf4, acc1[nt], 0, 0, 0);
            }
            __builtin_amdgcn_s_setprio(0);
        } else {
            bf16x8 bf[5];
            const f4v* hr = (const f4v*)(h + (size_t)row * HD);
            const f4v* hc = (const f4v*)(h + (size_t)col * HD);
#pragma unroll
            for (int s = 0; s < 4; ++s) {
                const f4v* src = (s < 2) ? hr : hc;
                f4v a = src[(s & 1) * 8 + q * 2];
                f4v b = src[(s & 1) * 8 + q * 2 + 1];
                bf[s] = pack_f8(a, b);
            }
            bf[4] = bf4;
#pragma unroll
            for (int s = 0; s < 5; ++s) {
#pragma unroll
                for (int nt = 0; nt < 4; ++nt) {
                    bf16x8 afrag = *(const bf16x8*)(sW1 + (16 * nt + m) * SAS + s * 32 + q * 8);
                    acc1[nt] = __builtin_amdgcn_mfma_f32_16x16x32_bf16(afrag, bf[s], acc1[nt], 0, 0, 0);
                }
            }
        }

        // silu(fmaf(acc1, sc, b1)) -> X1; sc folds the fp8 x8 pre-scale
        const float sc = HB ? 0.125f : 1.0f;
#pragma unroll
        for (int nt = 0; nt < 4; ++nt) {
            float4 bb = *(const float4*)(&sB1[16 * nt + 4 * q]);
            float s0, s1, s2, s3;
            silu2(fmaf(acc1[nt][0], sc, bb.x), fmaf(acc1[nt][1], sc, bb.y), s0, s1);
            silu2(fmaf(acc1[nt][2], sc, bb.z), fmaf(acc1[nt][3], sc, bb.w), s2, s3);
            if (HB) {
                int p = __builtin_amdgcn_cvt_pk_fp8_f32(s0, s1, 0, false);
                p     = __builtin_amdgcn_cvt_pk_fp8_f32(s2, s3, p, true);
                *((unsigned*)(x1RowB + 16 * nt + 4 * q)) = (unsigned)p;
            } else {
                uint2 o;
                o.x = cvt_pk_bf16(s0, s1);
                o.y = cvt_pk_bf16(s2, s3);
                *((uint2*)(x1Row + 16 * nt + 4 * q)) = o;
            }
        }

        // ---------- layer 2 ----------
        f32x4 acc2[4] = {};
        __builtin_amdgcn_s_setprio(1);
        if (HB) {
#pragma unroll
            for (int s = 0; s < 2; ++s) {
                long bfrag = *(const long*)(x1RowB + s * 32 + q * 8);
#pragma unroll
                for (int nt = 0; nt < 4; ++nt) {
                    long a8 = (long)sW2f8[((nt << 1) | s) * 64 + lane];
                    acc2[nt] = __builtin_amdgcn_mfma_f32_16x16x32_fp8_fp8(a8, bfrag, acc2[nt], 0, 0, 0);
                }
            }
        } else {
#pragma unroll
            for (int s = 0; s < 2; ++s) {
                bf16x8 bfrag = *(const bf16x8*)(x1Row + s * 32 + q * 8);
#pragma unroll
                for (int nt = 0; nt < 4; ++nt) {
                    bf16x8 afrag = *(const bf16x8*)(sW2 + (16 * nt + m) * W2S + s * 32 + q * 8);
                    acc2[nt] = __builtin_amdgcn_mfma_f32_16x16x32_bf16(afrag, bfrag, acc2[nt], 0, 0, 0);
                }
            }
        }
        __builtin_amdgcn_s_setprio(0);

        // ---------- epilogue: scal = silu(X2) . W3 (pair-rcp silu) ----------
        const float sc2 = HB ? 0.125f : 1.0f;
        float p = 0.f;
#pragma unroll
        for (int nt = 0; nt < 4; ++nt) {
            float4 b2v2 = *(const float4*)(&sB2[16 * nt + 4 * q]);
            float4 w3v  = *(const float4*)(&sW3[16 * nt + 4 * q]);
            float s0, s1, s2, s3;
            silu2(fmaf(acc2[nt][0], sc2, b2v2.x), fmaf(acc2[nt][1], sc2, b2v2.y), s0, s1);
            silu2(fmaf(acc2[nt][2], sc2, b2v2.z), fmaf(acc2[nt][3], sc2, b2v2.w), s2, s3);
            p = fmaf(s0, w3v.x, p);
            p = fmaf(s1, w3v.y, p);
            p = fmaf(s2, w3v.z, p);
            p = fmaf(s3, w3v.w, p);
        }
        p += __shfl_xor(p, 16);
        p += __shfl_xor(p, 32);

        float cd = cr - cc;
        float r2 = cd * cd;
        r2 += __shfl_xor(r2, 16);
        r2 += __shfl_xor(r2, 32);
        if (e < E_ && q < 3) {
            float inv = __builtin_amdgcn_rcpf(sqrtf(r2 + 1e-8f) + 1.0f);
            atomicAdd(&osink[row * 3 + q], cd * (p * NORM_INV * inv));
        }
    }
}

extern "C" void kernel_launch(void* const* d_in, const int* in_sizes, int n_in,
                              void* d_out, int out_size, void* d_ws, size_t ws_size,
                              hipStream_t stream) {
    const float* h         = (const float*)d_in[0];
    const float* coord     = (const float*)d_in[1];
    const int*   eidx      = (const int*)  d_in[2];
    const float* edge_attr = (const float*)d_in[3];
    const float* W1        = (const float*)d_in[4];
    const float* b1        = (const float*)d_in[5];
    const float* W2        = (const float*)d_in[6];
    const float* b2        = (const float*)d_in[7];
    const float* W3        = (const float*)d_in[8];
    float* out = (float*)d_out;

    int E_ = in_sizes[2] / 2;    // edge_index is [2, E]
    int n3 = out_size;           // N*3
    int nf = in_sizes[0];        // N*HD floats of h

    size_t hfbytes = (size_t)nf;            // fp8 table = nf bytes (3.2 MB)
    if (ws_size >= hfbytes) {
        unsigned char* hf8 = (unsigned char*)d_ws;
        int ncopies = 1;
        if (ws_size >= hfbytes + 32ull * (size_t)n3)      ncopies = 8;
        else if (ws_size >= hfbytes + 16ull * (size_t)n3) ncopies = 4;
        float* copies = (float*)((char*)d_ws + hfbytes);  // nf is 16B-aligned
        int zcount = (ncopies > 1) ? ncopies * n3 : 0;

        int nq = nf / 4;
        int pgrid = (nq > n3 ? nq : n3);
        hipLaunchKernelGGL(prep_h_kernel, dim3((pgrid + 255) / 256), dim3(256), 0, stream,
                           h, hf8, nq, coord, out, n3, copies, zcount);
        hipLaunchKernelGGL((egnn_mfma_kernel<true>), dim3(NBLK), dim3(NTH), 0, stream,
                           h, hf8, coord, eidx, edge_attr, W1, W2, b1, b2, W3,
                           (ncopies > 1 ? copies : out), ncopies - 1, n3, E_);
        if (ncopies > 1)
            hipLaunchKernelGGL(reduce_out_kernel, dim3((n3 + 255) / 256), dim3(256), 0, stream,
                               coord, copies, out, n3, ncopies);
    } else {
        hipLaunchKernelGGL(prep_out_kernel, dim3((n3 + 255) / 256), dim3(256), 0, stream,
                           coord, out, n3);
        hipLaunchKernelGGL((egnn_mfma_kernel<false>), dim3(NBLK), dim3(NTH), 0, stream,
                           h, (const unsigned char*)nullptr, coord, eidx, edge_attr,
                           W1, W2, b1, b2, W3, out, 0, n3, E_);
    }
}

// Round 14
// 221.761 us; speedup vs baseline: 1.0340x; 1.0340x over previous
//
#include <hip/hip_runtime.h>
#include <math.h>

#define HD   64
#define EIN  8
#define SAS  168          // !HB: full bf16 W1 row stride in u16
#define W2S  72           // !HB: sW2/X1 row stride in u16 (144 B)
#define X1BS 72           // HB: X1 fp8 row stride in BYTES (16 banks, conflict-free)
#define NORM_INV 0.01f
#define NTH  256
#define NBLK 1536         // 6 blocks/CU: proven optimum (r14/r16 A/B)
#define NWAVES (NBLK * (NTH / 64))

typedef short bf16x8 __attribute__((ext_vector_type(8)));
typedef float f32x4  __attribute__((ext_vector_type(4)));
typedef float f4v    __attribute__((ext_vector_type(4)));

// anti-remat / wait-anchor: "+v" makes this asm the reaching def AND the
// first USE of x -- placed at END of body so the s_waitcnt for x's load
// lands after the full compute phase, not at the head of the next iteration.
#define PINV(x) asm volatile("" : "+v"(x))

__device__ __forceinline__ unsigned short f2bf(float f) {
    union { float f; unsigned u; } v; v.f = f;
    unsigned r = v.u + 0x7FFFu + ((v.u >> 16) & 1u);
    return (unsigned short)(r >> 16);
}
__device__ __forceinline__ unsigned pk2(float a, float b) {
    return (unsigned)f2bf(a) | ((unsigned)f2bf(b) << 16);
}
// single-instruction packed f32->2xbf16 (RNE)
__device__ __forceinline__ unsigned cvt_pk_bf16(float lo, float hi) {
    unsigned r;
    asm("v_cvt_pk_bf16_f32 %0, %1, %2" : "=v"(r) : "v"(lo), "v"(hi));
    return r;
}
__device__ __forceinline__ float silu_f(float x) {
    return x * __builtin_amdgcn_rcpf(1.0f + __expf(-x));
}
// pair-silu: ONE rcp for two values (exact algebra, one extra rounding)
__device__ __forceinline__ void silu2(float x, float y, float& sx, float& sy) {
    float a = 1.0f + __expf(-x);
    float b = 1.0f + __expf(-y);
    float r = __builtin_amdgcn_rcpf(a * b);
    sx = x * (b * r);
    sy = y * (a * r);
}
__device__ __forceinline__ bf16x8 pack_f8(f4v a, f4v b) {
    union { bf16x8 v; uint4 u; } pk;
    pk.u.x = pk2(a.x, a.y); pk.u.y = pk2(a.z, a.w);
    pk.u.z = pk2(b.x, b.y); pk.u.w = pk2(b.z, b.w);
    return pk.v;
}

// prep: h -> fp8 e4m3 table in ws (3.2 MB -> L2-resident per XCD) + coord -> out
__global__ void prep_h_kernel(const float* __restrict__ h, unsigned char* __restrict__ hf8,
                              int nq, const float* __restrict__ coord,
                              float* __restrict__ out, int n3) {
    int i = blockIdx.x * blockDim.x + threadIdx.x;
    if (i < nq) {
        f4v v = reinterpret_cast<const f4v*>(h)[i];
        int p = __builtin_amdgcn_cvt_pk_fp8_f32(v.x, v.y, 0, false);
        p     = __builtin_amdgcn_cvt_pk_fp8_f32(v.z, v.w, p, true);
        reinterpret_cast<int*>(hf8)[i] = p;
    }
    if (i < n3) out[i] = coord[i];
}

__global__ void prep_out_kernel(const float* __restrict__ coord,
                                float* __restrict__ out, int n3) {
    int i = blockIdx.x * blockDim.x + threadIdx.x;
    if (i < n3) out[i] = coord[i];
}

// r19 ledger:
//  r18 (8-way partitioned accumulators): WRITE_SIZE byte-identical (62.4MB)
//    and dur flat -> fp atomics execute MEMORY-SIDE (~13B/op traffic,
//    proportional to op count not layout). No line ping-pong exists;
//    contention theory falsified; partition reverted.
//  Remaining un-eliminated latency term: eidx is a read-once HBM stream ->
//    ~900cy cold-miss at the HEAD of every iteration, before the dependent
//    hf8/coord gathers (~300cy) can issue. All prior prefetch attempts
//    carried 40+ VGPRs of fragments (spill/remat) or confounded layout
//    (r15 chunking). INDEX-ONLY prefetch = 4 regs, never cleanly tested.
//  r19: r14-exact body + 2-reg eidx prefetch one iter ahead, PINV at body
//    end (wait anchored after compute; no top-of-body use).
//  Keystones: VGPR 44-48 (40 = sunk again); FETCH ~70MB; occ ~53.
//  dur 90-105 if eidx-head was the binder; FLAT -> structural floor,
//  declare on r14 config next round.
template <bool HB>
__global__ __launch_bounds__(NTH, 5) void egnn_mfma_kernel(
    const float* __restrict__ h,             // fp32 h (when !HB)
    const unsigned char* __restrict__ hf8,   // fp8 h table in ws (when HB)
    const float* __restrict__ coord,
    const int*   __restrict__ eidx,   // [2][E]
    const float* __restrict__ eattr,  // [E][8]
    const float* __restrict__ W1f,    // [136][64] fp32 (k-major)
    const float* __restrict__ W2f,    // [64][64] fp32 (k-major)
    const float* __restrict__ b1,
    const float* __restrict__ b2,
    const float* __restrict__ W3,
    float* __restrict__ out,
    int E_)
{
    constexpr int LDS_BYTES = HB ? 18688 : 40704;
    __shared__ __align__(16) char lds[LDS_BYTES];

    unsigned long*  sW1f8 = (unsigned long*)lds;                         // HB
    unsigned short* sW1b  = (unsigned short*)(lds + 8192);               // HB
    unsigned long*  sW2f8 = (unsigned long*)(lds + 9216);                // HB
    unsigned char*  sX1b  = (unsigned char*)(lds + 13312);               // HB
    unsigned short* sW1   = (unsigned short*)lds;                        // !HB
    unsigned short* sW2   = (unsigned short*)(lds + 21504);              // !HB
    unsigned short* sX1   = (unsigned short*)(lds + 30720);              // !HB
    float*          sB1   = (float*)(lds + (HB ? 17920 : 39936));
    float*          sB2   = sB1 + 64;
    float*          sW3   = sB1 + 128;

    const int t = threadIdx.x;

    // ---- weights -> LDS (once per block) ----
    if (HB) {
        for (int f = t; f < 16 * 64; f += NTH) {
            int frag = f >> 6, ln = f & 63;
            int nt = frag >> 2, s = frag & 3;
            int mm = ln & 15, qq = ln >> 4;
            int n2 = nt * 16 + mm, kb = s * 32 + qq * 8;
            unsigned long v = 0;
#pragma unroll
            for (int j = 0; j < 8; j += 2) {
                float a = W1f[(kb + j) * 64 + n2] * 8.0f;
                float b = W1f[(kb + j + 1) * 64 + n2] * 8.0f;
                int p = __builtin_amdgcn_cvt_pk_fp8_f32(a, b, 0, false);
                v |= ((unsigned long)(unsigned)(p & 0xFFFF)) << (j * 8);
            }
            sW1f8[f] = v;
        }
        for (int i = t; i < 64 * 8; i += NTH) {
            int n2 = i >> 3, kk = i & 7;
            sW1b[i] = f2bf(W1f[(128 + kk) * 64 + n2]);
        }
        for (int f = t; f < 8 * 64; f += NTH) {
            int frag = f >> 6, ln = f & 63;
            int nt = frag >> 1, s = frag & 1;
            int mm = ln & 15, qq = ln >> 4;
            int n2 = nt * 16 + mm, kb = s * 32 + qq * 8;
            unsigned long v = 0;
#pragma unroll
            for (int j = 0; j < 8; j += 2) {
                float a = W2f[(kb + j) * 64 + n2] * 8.0f;
                float b = W2f[(kb + j + 1) * 64 + n2] * 8.0f;
                int p = __builtin_amdgcn_cvt_pk_fp8_f32(a, b, 0, false);
                v |= ((unsigned long)(unsigned)(p & 0xFFFF)) << (j * 8);
            }
            sW2f8[f] = v;
        }
    } else {
        for (int i = t; i < 136 * 64; i += NTH) {
            int k = i >> 6, n = i & 63;
            sW1[n * SAS + k] = f2bf(W1f[i]);
        }
        for (int i = t; i < 24 * 64; i += NTH) {
            int n = i / 24, k = 136 + (i - n * 24);
            sW1[n * SAS + k] = 0;
        }
        for (int i = t; i < 64 * 64; i += NTH) {
            int k = i >> 6, n = i & 63;
            sW2[n * W2S + k] = f2bf(W2f[i]);
        }
    }
    if (t < 64) sB1[t] = b1[t];
    else if (t < 128) sB2[t - 64] = b2[t - 64];
    else if (t < 192) sW3[t - 128] = W3[t - 128];
    __syncthreads();                               // the ONLY barrier

    const int w = t >> 6, lane = t & 63;
    const int m = lane & 15, q = lane >> 4;

    unsigned char*  x1RowB = sX1b + (16 * w + m) * X1BS;          // HB
    unsigned short* x1Row  = sX1 + (16 * w + m) * W2S;            // !HB

    const int ngroups = (E_ + 15) >> 4;
    const int g0 = blockIdx.x * (NTH / 64) + w;

#define IDXLD(G, R, C) do {                                             \
    int e_ = (G) * 16 + m;                                              \
    int ec_ = (e_ < E_) ? e_ : (E_ - 1);                                \
    R = __builtin_nontemporal_load(eidx + ec_);                         \
    C = __builtin_nontemporal_load(eidx + (size_t)E_ + ec_);            \
} while (0)

    // index pipeline: row_c/col_c for CURRENT group are resident at loop top
    int row_c = 0, col_c = 0;
    if (g0 < ngroups) IDXLD(g0, row_c, col_c);

    for (int g = g0; g < ngroups; g += NWAVES) {
        int e = g * 16 + m;
        int ec = (e < E_) ? e : (E_ - 1);

        // -------- prefetch NEXT group's indices (2 regs, in flight all body) --------
        int row_n = 0, col_n = 0;
        const int gn = g + NWAVES;
        if (gn < ngroups) IDXLD(gn, row_n, col_n);

        // current gathers issue immediately (indices already resident)
        float cr = 0.f, cc = 0.f;
        if (q < 3) { cr = coord[row_c * 3 + q]; cc = coord[col_c * 3 + q]; }

        // ---------- eattr fragment (bf16, k=128..135 on q==0) ----------
        bf16x8 bf4;
        {
            union { bf16x8 v; uint4 u; } pk;
            pk.u.x = 0; pk.u.y = 0; pk.u.z = 0; pk.u.w = 0;
            if (q == 0) {
                const f4v* ea = (const f4v*)(eattr + (size_t)ec * EIN);
                f4v a0 = __builtin_nontemporal_load(ea);
                f4v a1 = __builtin_nontemporal_load(ea + 1);
                pk.u.x = cvt_pk_bf16(a0.x, a0.y);
                pk.u.y = cvt_pk_bf16(a0.z, a0.w);
                pk.u.z = cvt_pk_bf16(a1.x, a1.y);
                pk.u.w = cvt_pk_bf16(a1.z, a1.w);
            }
            bf4 = pk.v;
        }

        f32x4 acc1[4] = {};

        if (HB) {
            // ---------- layer-1 h-part: fp8 gathers (8 B each, L2-resident) ----------
            const unsigned long* hr8 = (const unsigned long*)(hf8 + (size_t)row_c * HD);
            const unsigned long* hc8 = (const unsigned long*)(hf8 + (size_t)col_c * HD);
            long b0 = (long)hr8[q];         // k =      q*8
            long b1v = (long)hr8[4 + q];    // k = 32 + q*8
            long b2v = (long)hc8[q];        // k = 64 + ...
            long b3v = (long)hc8[4 + q];    // k = 96 + ...
            __builtin_amdgcn_s_setprio(1);
#define L1F8(S, B)                                                            \
            _Pragma("unroll")                                                 \
            for (int nt = 0; nt < 4; ++nt) {                                  \
                long a8 = (long)sW1f8[((nt << 2) | (S)) * 64 + lane];         \
                acc1[nt] = __builtin_amdgcn_mfma_f32_16x16x32_fp8_fp8(a8, B, acc1[nt], 0, 0, 0); \
            }
            L1F8(0, b0)
            L1F8(1, b1v)
            L1F8(2, b2v)
            L1F8(3, b3v)
#undef L1F8
            // eattr tail (bf16 MFMA): broadcast-read, q>=1 slices killed by zeros.
#pragma unroll
            for (int nt = 0; nt < 4; ++nt) {
                bf16x8 afb = *(const bf16x8*)(sW1b + (16 * nt + m) * 8);
                acc1[nt] = __builtin_amdgcn_mfma_f32_16x16x32_bf16(afb, bf4, acc1[nt], 0, 0, 0);
            }
            __builtin_amdgcn_s_setprio(0);
        } else {
            bf16x8 bf[5];
            const f4v* hr = (const f4v*)(h + (size_t)row_c * HD);
            const f4v* hc = (const f4v*)(h + (size_t)col_c * HD);
#pragma unroll
            for (int s = 0; s < 4; ++s) {
                const f4v* src = (s < 2) ? hr : hc;
                f4v a = src[(s & 1) * 8 + q * 2];
                f4v b = src[(s & 1) * 8 + q * 2 + 1];
                bf[s] = pack_f8(a, b);
            }
            bf[4] = bf4;
#pragma unroll
            for (int s = 0; s < 5; ++s) {
#pragma unroll
                for (int nt = 0; nt < 4; ++nt) {
                    bf16x8 afrag = *(const bf16x8*)(sW1 + (16 * nt + m) * SAS + s * 32 + q * 8);
                    acc1[nt] = __builtin_amdgcn_mfma_f32_16x16x32_bf16(afrag, bf[s], acc1[nt], 0, 0, 0);
                }
            }
        }

        // silu(fmaf(acc1, sc, b1)) -> X1; sc folds the fp8 x8 pre-scale
        const float sc = HB ? 0.125f : 1.0f;
#pragma unroll
        for (int nt = 0; nt < 4; ++nt) {
            float4 bb = *(const float4*)(&sB1[16 * nt + 4 * q]);
            float s0, s1, s2, s3;
            silu2(fmaf(acc1[nt][0], sc, bb.x), fmaf(acc1[nt][1], sc, bb.y), s0, s1);
            silu2(fmaf(acc1[nt][2], sc, bb.z), fmaf(acc1[nt][3], sc, bb.w), s2, s3);
            if (HB) {
                int p = __builtin_amdgcn_cvt_pk_fp8_f32(s0, s1, 0, false);
                p     = __builtin_amdgcn_cvt_pk_fp8_f32(s2, s3, p, true);
                *((unsigned*)(x1RowB + 16 * nt + 4 * q)) = (unsigned)p;
            } else {
                uint2 o;
                o.x = cvt_pk_bf16(s0, s1);
                o.y = cvt_pk_bf16(s2, s3);
                *((uint2*)(x1Row + 16 * nt + 4 * q)) = o;
            }
        }

        // ---------- layer 2 ----------
        f32x4 acc2[4] = {};
        __builtin_amdgcn_s_setprio(1);
        if (HB) {
#pragma unroll
            for (int s = 0; s < 2; ++s) {
                long bfrag = *(const long*)(x1RowB + s * 32 + q * 8);
#pragma unroll
                for (int nt = 0; nt < 4; ++nt) {
                    long a8 = (long)sW2f8[((nt << 1) | s) * 64 + lane];
                    acc2[nt] = __builtin_amdgcn_mfma_f32_16x16x32_fp8_fp8(a8, bfrag, acc2[nt], 0, 0, 0);
                }
            }
        } else {
#pragma unroll
            for (int s = 0; s < 2; ++s) {
                bf16x8 bfrag = *(const bf16x8*)(x1Row + s * 32 + q * 8);
#pragma unroll
                for (int nt = 0; nt < 4; ++nt) {
                    bf16x8 afrag = *(const bf16x8*)(sW2 + (16 * nt + m) * W2S + s * 32 + q * 8);
                    acc2[nt] = __builtin_amdgcn_mfma_f32_16x16x32_bf16(afrag, bfrag, acc2[nt], 0, 0, 0);
                }
            }
        }
        __builtin_amdgcn_s_setprio(0);

        // ---------- epilogue: scal = silu(X2) . W3 (pair-rcp silu) ----------
        const float sc2 = HB ? 0.125f : 1.0f;
        float p = 0.f;
#pragma unroll
        for (int nt = 0; nt < 4; ++nt) {
            float4 b2v2 = *(const float4*)(&sB2[16 * nt + 4 * q]);
            float4 w3v  = *(const float4*)(&sW3[16 * nt + 4 * q]);
            float s0, s1, s2, s3;
            silu2(fmaf(acc2[nt][0], sc2, b2v2.x), fmaf(acc2[nt][1], sc2, b2v2.y), s0, s1);
            silu2(fmaf(acc2[nt][2], sc2, b2v2.z), fmaf(acc2[nt][3], sc2, b2v2.w), s2, s3);
            p = fmaf(s0, w3v.x, p);
            p = fmaf(s1, w3v.y, p);
            p = fmaf(s2, w3v.z, p);
            p = fmaf(s3, w3v.w, p);
        }
        p += __shfl_xor(p, 16);
        p += __shfl_xor(p, 32);

        float cd = cr - cc;
        float r2 = cd * cd;
        r2 += __shfl_xor(r2, 16);
        r2 += __shfl_xor(r2, 32);
        if (e < E_ && q < 3) {
            float inv = __builtin_amdgcn_rcpf(sqrtf(r2 + 1e-8f) + 1.0f);
            atomicAdd(&out[row_c * 3 + q], cd * (p * NORM_INV * inv));
        }

        // -------- pin prefetched indices HERE (wait after compute) + rotate ----
        PINV(row_n); PINV(col_n);
        row_c = row_n; col_c = col_n;
    }
#undef IDXLD
}

extern "C" void kernel_launch(void* const* d_in, const int* in_sizes, int n_in,
                              void* d_out, int out_size, void* d_ws, size_t ws_size,
                              hipStream_t stream) {
    const float* h         = (const float*)d_in[0];
    const float* coord     = (const float*)d_in[1];
    const int*   eidx      = (const int*)  d_in[2];
    const float* edge_attr = (const float*)d_in[3];
    const float* W1        = (const float*)d_in[4];
    const float* b1        = (const float*)d_in[5];
    const float* W2        = (const float*)d_in[6];
    const float* b2        = (const float*)d_in[7];
    const float* W3        = (const float*)d_in[8];
    float* out = (float*)d_out;

    int E_ = in_sizes[2] / 2;    // edge_index is [2, E]
    int n3 = out_size;           // N*3
    int nf = in_sizes[0];        // N*HD floats of h

    if (ws_size >= (size_t)nf) {                 // fp8 h table (3.2 MB)
        unsigned char* hf8 = (unsigned char*)d_ws;
        int nq = nf / 4;
        int pgrid = (nq > n3 ? nq : n3);
        hipLaunchKernelGGL(prep_h_kernel, dim3((pgrid + 255) / 256), dim3(256), 0, stream,
                           h, hf8, nq, coord, out, n3);
        hipLaunchKernelGGL((egnn_mfma_kernel<true>), dim3(NBLK), dim3(NTH), 0, stream,
                           h, hf8, coord, eidx, edge_attr, W1, W2, b1, b2, W3, out, E_);
    } else {
        hipLaunchKernelGGL(prep_out_kernel, dim3((n3 + 255) / 256), dim3(256), 0, stream,
                           coord, out, n3);
        hipLaunchKernelGGL((egnn_mfma_kernel<false>), dim3(NBLK), dim3(NTH), 0, stream,
                           h, (const unsigned char*)nullptr, coord, eidx, edge_attr,
                           W1, W2, b1, b2, W3, out, E_);
    }
}